// Round 7
// baseline (473.882 us; speedup 1.0000x reference)
//
#include <hip/hip_runtime.h>
#include <math.h>

#define NEG_SLOPE 0.01f
#define ELLW 40   // max in-degree per relation (Poisson(10); P(overflow)~1e-8, clamped)

typedef float f4 __attribute__((ext_vector_type(4)));
typedef __bf16 bf16x8 __attribute__((ext_vector_type(8)));
typedef __bf16 bf16x4 __attribute__((ext_vector_type(4)));

// inv[i] = rsqrt(max(deg[i],1)) over the concatenated degree region
__global__ __launch_bounds__(256) void finalize_deg(const int* __restrict__ deg,
    float* __restrict__ inv, int n)
{
    int i = blockIdx.x * 256 + threadIdx.x;
    if (i < n) {
        float d = (float)deg[i];
        inv[i] = rsqrtf(fmaxf(d, 1.0f));
    }
}

// ---------------- W prep: transpose + bf16 split (5 weights) ----------------
__global__ __launch_bounds__(256) void prep_w(
    const float* __restrict__ W0, const float* __restrict__ W1,
    const float* __restrict__ W2, const float* __restrict__ W3,
    const float* __restrict__ W4, __bf16* __restrict__ H, __bf16* __restrict__ L)
{
    const int y = blockIdx.y;
    const float* W = y == 0 ? W0 : y == 1 ? W1 : y == 2 ? W2 : y == 3 ? W3 : W4;
    int idx = blockIdx.x * 256 + threadIdx.x;   // 0..16383
    int k = idx >> 7, n = idx & 127;
    float w = W[idx];
    __bf16 h = (__bf16)w;
    __bf16 l = (__bf16)(w - (float)h);
    H[(size_t)y * 16384 + n * 128 + k] = h;
    L[(size_t)y * 16384 + n * 128 + k] = l;
}

// ---------------- MFMA GEMM core (bf16 3-split, unscaled): C[BM rows,128] = f(A) @ W ----------------
// MI=2 -> BM=64 (34.8 KB LDS); MI=1 -> BM=32 (17.4 KB LDS, for fused-kernel occupancy)
template <int RELU, int MI>
__device__ __forceinline__ void gemm_core(const float* __restrict__ A,
    const __bf16* __restrict__ Bh, const __bf16* __restrict__ Bl,
    float* __restrict__ C, int M, int row0, int tid,
    __bf16 (*Ah)[136], __bf16 (*Al)[136])
{
#pragma unroll
    for (int it = 0; it < MI * 4; ++it) {
        int idx4 = it * 256 + tid;
        int r = idx4 >> 5;
        int c = (idx4 & 31) << 2;
        int rg = row0 + r;
        f4 v = {0.f, 0.f, 0.f, 0.f};
        if (rg < M) v = *(const f4*)(A + (size_t)rg * 128 + c);
        if (RELU) {
#pragma unroll
            for (int j = 0; j < 4; ++j) v[j] = v[j] >= 0.f ? v[j] : v[j] * NEG_SLOPE;
        }
        bf16x4 hv, lv;
#pragma unroll
        for (int j = 0; j < 4; ++j) {
            __bf16 h = (__bf16)v[j];
            hv[j] = h;
            lv[j] = (__bf16)(v[j] - (float)h);
        }
        *(bf16x4*)&Ah[r][c] = hv;
        *(bf16x4*)&Al[r][c] = lv;
    }
    __syncthreads();

    const int lane = tid & 63;
    const int wid = tid >> 6;
    const int lm = lane & 15;
    const int lq = lane >> 4;
    const int mbase = (wid & 1) * (MI * 16);
    const int nbase = (wid >> 1) * 64;

    f4 acc[MI][4] = {};
#pragma unroll
    for (int kc = 0; kc < 4; ++kc) {
        const int koff = kc * 32 + lq * 8;
        bf16x8 ah[MI], al[MI], bh[4], bl[4];
#pragma unroll
        for (int mi = 0; mi < MI; ++mi) {
            ah[mi] = *(const bf16x8*)&Ah[mbase + mi * 16 + lm][koff];
            al[mi] = *(const bf16x8*)&Al[mbase + mi * 16 + lm][koff];
        }
#pragma unroll
        for (int ni = 0; ni < 4; ++ni) {
            size_t boff = (size_t)(nbase + ni * 16 + lm) * 128 + koff;
            bh[ni] = *(const bf16x8*)(Bh + boff);
            bl[ni] = *(const bf16x8*)(Bl + boff);
        }
#pragma unroll
        for (int mi = 0; mi < MI; ++mi)
#pragma unroll
            for (int ni = 0; ni < 4; ++ni) {
                acc[mi][ni] = __builtin_amdgcn_mfma_f32_16x16x32_bf16(ah[mi], bh[ni], acc[mi][ni], 0, 0, 0);
                acc[mi][ni] = __builtin_amdgcn_mfma_f32_16x16x32_bf16(al[mi], bh[ni], acc[mi][ni], 0, 0, 0);
                acc[mi][ni] = __builtin_amdgcn_mfma_f32_16x16x32_bf16(ah[mi], bl[ni], acc[mi][ni], 0, 0, 0);
            }
    }

#pragma unroll
    for (int mi = 0; mi < MI; ++mi) {
        int rbase = row0 + mbase + mi * 16 + lq * 4;
#pragma unroll
        for (int r = 0; r < 4; ++r) {
            int row = rbase + r;
            if (row < M) {
#pragma unroll
                for (int ni = 0; ni < 4; ++ni)
                    C[(size_t)row * 128 + nbase + ni * 16 + lm] = acc[mi][ni][r];
            }
        }
    }
}

// ---------------- fused: graph build (atomics) + layer-1 GEMMs (BM=32, 17.4KB LDS) ----------------
// blockIdx.x % 4 in {0,1,2} -> GEMM tile; == 3 -> 1024 edges of build (4/thread).
__global__ __launch_bounds__(256) void fused_build_gemm(
    const int* __restrict__ s0, const int* __restrict__ d0, int* sd0, int* c0, int* e0, int E0, int B0,
    const int* __restrict__ s1, const int* __restrict__ d1, int* sd1, int* c1, int* e1, int E1, int B1,
    const int* __restrict__ s2, const int* __restrict__ d2, int* sd2, int* c2, int* e2, int E2,
    const float* __restrict__ xc, const float* __restrict__ xg,
    const __bf16* __restrict__ wt_h, const __bf16* __restrict__ wt_l,
    float* __restrict__ t_cg, float* __restrict__ t_cc, float* __restrict__ t_gc,
    int Nc, int Ng, int gBc, int G, int EB)
{
    __shared__ __bf16 Ah[32][136];
    __shared__ __bf16 Al[32][136];
    const int idx = blockIdx.x;
    const int r4 = idx & 3, q = idx >> 2;
    if (r4 < 3) {
        int g = q * 3 + r4;
        if (g >= G) return;
        if (g < gBc)
            gemm_core<0, 1>(xc, wt_h, wt_l, t_cg, Nc, g * 32, threadIdx.x, Ah, Al);
        else if (g < 2 * gBc)
            gemm_core<0, 1>(xc, wt_h + 16384, wt_l + 16384, t_cc, Nc, (g - gBc) * 32, threadIdx.x, Ah, Al);
        else
            gemm_core<0, 1>(xg, wt_h + 2 * 16384, wt_l + 2 * 16384, t_gc, Ng, (g - 2 * gBc) * 32, threadIdx.x, Ah, Al);
    } else {
        int eb = q;
        if (eb >= EB) return;
        const int* src; const int* dst; int* sdeg; int* cnt; int* ell; int E; int base;
        if (eb < B0)            { src = s0; dst = d0; sdeg = sd0; cnt = c0; ell = e0; E = E0; base = eb; }
        else if (eb < B0 + B1)  { src = s1; dst = d1; sdeg = sd1; cnt = c1; ell = e1; E = E1; base = eb - B0; }
        else                    { src = s2; dst = d2; sdeg = sd2; cnt = c2; ell = e2; E = E2; base = eb - B0 - B1; }
        int i0 = base * 1024 + threadIdx.x;
        int sv[4], dv[4];
        bool ok[4];
#pragma unroll
        for (int j = 0; j < 4; ++j) {
            int ii = i0 + j * 256;
            ok[j] = ii < E;
            sv[j] = ok[j] ? src[ii] : 0;
            dv[j] = ok[j] ? dst[ii] : 0;
        }
#pragma unroll
        for (int j = 0; j < 4; ++j)
            if (ok[j]) atomicAdd(&sdeg[sv[j]], 1);
        int p[4];
#pragma unroll
        for (int j = 0; j < 4; ++j)
            p[j] = ok[j] ? atomicAdd(&cnt[dv[j]], 1) : ELLW;
#pragma unroll
        for (int j = 0; j < 4; ++j)
            if (ok[j] && p[j] < ELLW) ell[dv[j] * ELLW + p[j]] = sv[j];
    }
}

// ---------------- standalone layer-2 GEMM (relu fused, BM=64) ----------------
__global__ __launch_bounds__(256) void gemm_relu(const float* __restrict__ A,
    const __bf16* __restrict__ Bh, const __bf16* __restrict__ Bl,
    float* __restrict__ C, int M)
{
    __shared__ __bf16 Ah[64][136];
    __shared__ __bf16 Al[64][136];
    gemm_core<1, 2>(A, Bh, Bl, C, M, blockIdx.x * 64, threadIdx.x, Ah, Al);
}

// ---------------- gather (ELL): per-edge src-norm scale, one wave per dst row ----------------
template <int DUAL>
__global__ __launch_bounds__(256) void gather_rows(
    const float* __restrict__ featA, const int* __restrict__ ellA,
    const int* __restrict__ cntA, const float* __restrict__ invA, const float* __restrict__ sclA,
    const float* __restrict__ featB, const int* __restrict__ ellB,
    const int* __restrict__ cntB, const float* __restrict__ invB, const float* __restrict__ sclB,
    const float* __restrict__ biasA, const float* __restrict__ biasB,
    float* __restrict__ out, int Nd)
{
    int lane = threadIdx.x & 63;
    int row = blockIdx.x * 4 + (threadIdx.x >> 6);
    if (row >= Nd) return;
    int c2 = lane * 2;

    float a0 = 0.f, a1 = 0.f;
    {
        int n = cntA[row];
        if (n > ELLW) n = ELLW;
        const int* cp = ellA + row * ELLW;
        int i = 0;
        for (; i + 3 < n; i += 4) {
            int q0 = cp[i], q1 = cp[i + 1], q2 = cp[i + 2], q3 = cp[i + 3];
            float w0 = sclA[q0], w1 = sclA[q1], w2 = sclA[q2], w3 = sclA[q3];
            float2 v0 = *(const float2*)(featA + (size_t)q0 * 128 + c2);
            float2 v1 = *(const float2*)(featA + (size_t)q1 * 128 + c2);
            float2 v2 = *(const float2*)(featA + (size_t)q2 * 128 + c2);
            float2 v3 = *(const float2*)(featA + (size_t)q3 * 128 + c2);
            a0 = fmaf(v0.x, w0, a0); a1 = fmaf(v0.y, w0, a1);
            a0 = fmaf(v1.x, w1, a0); a1 = fmaf(v1.y, w1, a1);
            a0 = fmaf(v2.x, w2, a0); a1 = fmaf(v2.y, w2, a1);
            a0 = fmaf(v3.x, w3, a0); a1 = fmaf(v3.y, w3, a1);
        }
        for (; i < n; ++i) {
            int q0 = cp[i];
            float w0 = sclA[q0];
            float2 v0 = *(const float2*)(featA + (size_t)q0 * 128 + c2);
            a0 = fmaf(v0.x, w0, a0); a1 = fmaf(v0.y, w0, a1);
        }
    }
    float wa = invA[row];
    float r0 = fmaf(a0, wa, biasA[c2]);
    float r1 = fmaf(a1, wa, biasA[c2 + 1]);

    if (DUAL) {
        float s0 = 0.f, s1 = 0.f;
        int n = cntB[row];
        if (n > ELLW) n = ELLW;
        const int* cp = ellB + row * ELLW;
        int i = 0;
        for (; i + 3 < n; i += 4) {
            int q0 = cp[i], q1 = cp[i + 1], q2 = cp[i + 2], q3 = cp[i + 3];
            float w0 = sclB[q0], w1 = sclB[q1], w2 = sclB[q2], w3 = sclB[q3];
            float2 v0 = *(const float2*)(featB + (size_t)q0 * 128 + c2);
            float2 v1 = *(const float2*)(featB + (size_t)q1 * 128 + c2);
            float2 v2 = *(const float2*)(featB + (size_t)q2 * 128 + c2);
            float2 v3 = *(const float2*)(featB + (size_t)q3 * 128 + c2);
            s0 = fmaf(v0.x, w0, s0); s1 = fmaf(v0.y, w0, s1);
            s0 = fmaf(v1.x, w1, s0); s1 = fmaf(v1.y, w1, s1);
            s0 = fmaf(v2.x, w2, s0); s1 = fmaf(v2.y, w2, s1);
            s0 = fmaf(v3.x, w3, s0); s1 = fmaf(v3.y, w3, s1);
        }
        for (; i < n; ++i) {
            int q0 = cp[i];
            float w0 = sclB[q0];
            float2 v0 = *(const float2*)(featB + (size_t)q0 * 128 + c2);
            s0 = fmaf(v0.x, w0, s0); s1 = fmaf(v0.y, w0, s1);
        }
        float wb = invB[row];
        r0 += fmaf(s0, wb, biasB[c2]);
        r1 += fmaf(s1, wb, biasB[c2 + 1]);
    }
    *(float2*)(out + (size_t)row * 128 + c2) = make_float2(r0, r1);
}

extern "C" void kernel_launch(void* const* d_in, const int* in_sizes, int n_in,
                              void* d_out, int out_size, void* d_ws, size_t ws_size,
                              hipStream_t stream)
{
    const float* x_chem = (const float*)d_in[0];
    const float* x_gene = (const float*)d_in[1];
    const int* src_cc = (const int*)d_in[2];
    const int* dst_cc = (const int*)d_in[3];
    const int* src_cg = (const int*)d_in[4];
    const int* dst_cg = (const int*)d_in[5];
    const int* src_gc = (const int*)d_in[6];
    const int* dst_gc = (const int*)d_in[7];
    const float* W1_cc = (const float*)d_in[8];
    const float* W1_cg = (const float*)d_in[9];
    const float* W1_gc = (const float*)d_in[10];
    const float* W2_cc = (const float*)d_in[11];
    const float* W2_gc = (const float*)d_in[13];
    const float* b1_cc = (const float*)d_in[14];
    const float* b1_cg = (const float*)d_in[15];
    const float* b1_gc = (const float*)d_in[16];
    const float* b2_cc = (const float*)d_in[17];
    const float* b2_gc = (const float*)d_in[19];
    (void)n_in; (void)out_size; (void)ws_size;

    const int Nc = in_sizes[0] / 128;
    const int Ng = in_sizes[1] / 128;
    const int Ecc = in_sizes[2];
    const int Ecg = in_sizes[4];
    const int Egc = in_sizes[6];

    // ---------------- workspace layout ----------------
    int* ip = (int*)d_ws;
    int* cnt_cc  = ip; ip += Nc;   // in-deg cc (zeroed)
    int* cnt_cg  = ip; ip += Ng;   // in-deg cg
    int* cnt_gc  = ip; ip += Nc;   // in-deg gc
    int* degs_cc = ip; ip += Nc;   // out-deg chem (cc)
    int* degs_cg = ip; ip += Nc;   // out-deg chem (cg)
    int* degs_gc = ip; ip += Ng;   // out-deg gene (gc)
    const int degTotal = 4 * Nc + 2 * Ng;
    int* ell_cc = ip; ip += (size_t)Nc * ELLW;
    int* ell_cg = ip; ip += (size_t)Ng * ELLW;
    int* ell_gc = ip; ip += (size_t)Nc * ELLW;
    size_t intCount = (size_t)(ip - (int*)d_ws);
    intCount = (intCount + 3) & ~(size_t)3;
    float* fp = (float*)d_ws + intCount;
    float* inv = fp; fp += degTotal;   // same order as degree region
    float* inv_dst_cc = inv;
    float* inv_dst_cg = inv + Nc;
    float* inv_dst_gc = inv + Nc + Ng;
    float* inv_src_cc = inv + 2 * Nc + Ng;
    float* inv_src_cg = inv + 3 * Nc + Ng;
    float* inv_src_gc = inv + 4 * Nc + Ng;
    float* h1_chem = fp; fp += (size_t)Nc * 128;
    float* h1_gene = fp; fp += (size_t)Ng * 128;
    float* tmp_cg  = fp; fp += (size_t)Nc * 128;   // layer1 cg out; reused as layer2 cc out
    float* tmp_gc  = fp; fp += (size_t)Ng * 128;   // layer1 gc out; reused as layer2 gc out
    __bf16* wt_h = (__bf16*)fp;                    // 5 * 16384 bf16
    __bf16* wt_l = wt_h + 5 * 16384;
    float* outF = (float*)d_out;                   // doubles as layer1 cc scratch

    hipMemsetAsync(d_ws, 0, (size_t)degTotal * sizeof(int), stream);

    dim3 blk(256);
    const int B0 = (Ecc + 1023) / 1024, B1 = (Ecg + 1023) / 1024, B2 = (Egc + 1023) / 1024;
    const int EB = B0 + B1 + B2;
    const int gBc = (Nc + 31) / 32, gBg = (Ng + 31) / 32;
    const int G = 2 * gBc + gBg;
    int Q = (G + 2) / 3;
    if (EB > Q) Q = EB;
    const int T = 4 * Q;

    // W prep (feeds the fused kernel's GEMM blocks)
    prep_w<<<dim3(64, 5), blk, 0, stream>>>(W1_cg, W1_cc, W1_gc, W2_cc, W2_gc, wt_h, wt_l);

    // fused: graph build + all three layer-1 GEMMs (unscaled)
    fused_build_gemm<<<T, blk, 0, stream>>>(
        src_cc, dst_cc, degs_cc, cnt_cc, ell_cc, Ecc, B0,
        src_cg, dst_cg, degs_cg, cnt_cg, ell_cg, Ecg, B1,
        src_gc, dst_gc, degs_gc, cnt_gc, ell_gc, Egc,
        x_chem, x_gene, wt_h, wt_l, tmp_cg, outF, tmp_gc,
        Nc, Ng, gBc, G, EB);

    finalize_deg<<<(degTotal + 255) / 256, blk, 0, stream>>>(cnt_cc, inv, degTotal);

    // ---- layer 1 gathers (apply inv_src per edge, inv_dst per row) ----
    gather_rows<0><<<(Ng + 3) / 4, blk, 0, stream>>>(
        tmp_cg, ell_cg, cnt_cg, inv_dst_cg, inv_src_cg,
        nullptr, nullptr, nullptr, nullptr, nullptr, b1_cg, nullptr, h1_gene, Ng);
    gather_rows<1><<<(Nc + 3) / 4, blk, 0, stream>>>(
        outF, ell_cc, cnt_cc, inv_dst_cc, inv_src_cc,
        tmp_gc, ell_gc, cnt_gc, inv_dst_gc, inv_src_gc,
        b1_cc, b1_gc, h1_chem, Nc);

    // ---- layer 2 ----
    gemm_relu<<<(Nc + 63) / 64, blk, 0, stream>>>(h1_chem, wt_h + 3 * 16384, wt_l + 3 * 16384, tmp_cg, Nc);
    gemm_relu<<<(Ng + 63) / 64, blk, 0, stream>>>(h1_gene, wt_h + 4 * 16384, wt_l + 4 * 16384, tmp_gc, Ng);
    gather_rows<1><<<(Nc + 3) / 4, blk, 0, stream>>>(
        tmp_cg, ell_cc, cnt_cc, inv_dst_cc, inv_src_cc,
        tmp_gc, ell_gc, cnt_gc, inv_dst_gc, inv_src_gc,
        b2_cc, b2_gc, outF, Nc);
}

// Round 8
// 443.543 us; speedup vs baseline: 1.0684x; 1.0684x over previous
//
#include <hip/hip_runtime.h>
#include <math.h>

#define NEG_SLOPE 0.01f
#define ELLW 40   // max in-degree per relation (Poisson(10); P(overflow)~1e-8, clamped)

typedef float f4 __attribute__((ext_vector_type(4)));
typedef __bf16 bf16x8 __attribute__((ext_vector_type(8)));
typedef __bf16 bf16x4 __attribute__((ext_vector_type(4)));

// ---------------- W prep: transpose + bf16 split (5 weights) ----------------
__global__ __launch_bounds__(256) void prep_w(
    const float* __restrict__ W0, const float* __restrict__ W1,
    const float* __restrict__ W2, const float* __restrict__ W3,
    const float* __restrict__ W4, __bf16* __restrict__ H, __bf16* __restrict__ L)
{
    const int y = blockIdx.y;
    const float* W = y == 0 ? W0 : y == 1 ? W1 : y == 2 ? W2 : y == 3 ? W3 : W4;
    int idx = blockIdx.x * 256 + threadIdx.x;   // 0..16383
    int k = idx >> 7, n = idx & 127;
    float w = W[idx];
    __bf16 h = (__bf16)w;
    __bf16 l = (__bf16)(w - (float)h);
    H[(size_t)y * 16384 + n * 128 + k] = h;
    L[(size_t)y * 16384 + n * 128 + k] = l;
}

// ---------------- MFMA GEMM core (bf16 3-split, unscaled): C[64 rows,128] = f(A) @ W ----------------
template <int RELU>
__device__ __forceinline__ void gemm_core(const float* __restrict__ A,
    const __bf16* __restrict__ Bh, const __bf16* __restrict__ Bl,
    float* __restrict__ C, int M, int row0, int tid,
    __bf16 (*Ah)[136], __bf16 (*Al)[136])
{
#pragma unroll
    for (int it = 0; it < 8; ++it) {
        int idx4 = it * 256 + tid;
        int r = idx4 >> 5;
        int c = (idx4 & 31) << 2;
        int rg = row0 + r;
        f4 v = {0.f, 0.f, 0.f, 0.f};
        if (rg < M) v = *(const f4*)(A + (size_t)rg * 128 + c);
        if (RELU) {
#pragma unroll
            for (int j = 0; j < 4; ++j) v[j] = v[j] >= 0.f ? v[j] : v[j] * NEG_SLOPE;
        }
        bf16x4 hv, lv;
#pragma unroll
        for (int j = 0; j < 4; ++j) {
            __bf16 h = (__bf16)v[j];
            hv[j] = h;
            lv[j] = (__bf16)(v[j] - (float)h);
        }
        *(bf16x4*)&Ah[r][c] = hv;
        *(bf16x4*)&Al[r][c] = lv;
    }
    __syncthreads();

    const int lane = tid & 63;
    const int wid = tid >> 6;
    const int lm = lane & 15;
    const int lq = lane >> 4;
    const int mbase = (wid & 1) * 32;
    const int nbase = (wid >> 1) * 64;

    f4 acc[2][4] = {};
#pragma unroll
    for (int kc = 0; kc < 4; ++kc) {
        const int koff = kc * 32 + lq * 8;
        bf16x8 ah[2], al[2], bh[4], bl[4];
#pragma unroll
        for (int mi = 0; mi < 2; ++mi) {
            ah[mi] = *(const bf16x8*)&Ah[mbase + mi * 16 + lm][koff];
            al[mi] = *(const bf16x8*)&Al[mbase + mi * 16 + lm][koff];
        }
#pragma unroll
        for (int ni = 0; ni < 4; ++ni) {
            size_t boff = (size_t)(nbase + ni * 16 + lm) * 128 + koff;
            bh[ni] = *(const bf16x8*)(Bh + boff);
            bl[ni] = *(const bf16x8*)(Bl + boff);
        }
#pragma unroll
        for (int mi = 0; mi < 2; ++mi)
#pragma unroll
            for (int ni = 0; ni < 4; ++ni) {
                acc[mi][ni] = __builtin_amdgcn_mfma_f32_16x16x32_bf16(ah[mi], bh[ni], acc[mi][ni], 0, 0, 0);
                acc[mi][ni] = __builtin_amdgcn_mfma_f32_16x16x32_bf16(al[mi], bh[ni], acc[mi][ni], 0, 0, 0);
                acc[mi][ni] = __builtin_amdgcn_mfma_f32_16x16x32_bf16(ah[mi], bl[ni], acc[mi][ni], 0, 0, 0);
            }
    }

#pragma unroll
    for (int mi = 0; mi < 2; ++mi) {
        int rbase = row0 + mbase + mi * 16 + lq * 4;
#pragma unroll
        for (int r = 0; r < 4; ++r) {
            int row = rbase + r;
            if (row < M) {
#pragma unroll
                for (int ni = 0; ni < 4; ++ni)
                    C[(size_t)row * 128 + nbase + ni * 16 + lm] = acc[mi][ni][r];
            }
        }
    }
}

// ---------------- fused: graph build (atomics, at scattered-RMW ceiling) + layer-1 GEMMs ----------------
// blockIdx.x % 7 in {0,1} -> GEMM tile (BM=64); else -> 256 edges of build (1/thread).
__global__ __launch_bounds__(256) void fused_build_gemm(
    const int* __restrict__ s0, const int* __restrict__ d0, int* sd0, int* c0, int* e0, int E0, int B0,
    const int* __restrict__ s1, const int* __restrict__ d1, int* sd1, int* c1, int* e1, int E1, int B1,
    const int* __restrict__ s2, const int* __restrict__ d2, int* sd2, int* c2, int* e2, int E2,
    const float* __restrict__ xc, const float* __restrict__ xg,
    const __bf16* __restrict__ wt_h, const __bf16* __restrict__ wt_l,
    float* __restrict__ t_cg, float* __restrict__ t_cc, float* __restrict__ t_gc,
    int Nc, int Ng, int gBc, int G, int EB)
{
    __shared__ __bf16 Ah[64][136];
    __shared__ __bf16 Al[64][136];
    const int idx = blockIdx.x;
    const int r7 = idx % 7, q = idx / 7;
    if (r7 < 2) {
        int g = q * 2 + r7;
        if (g >= G) return;
        if (g < gBc)
            gemm_core<0>(xc, wt_h, wt_l, t_cg, Nc, g * 64, threadIdx.x, Ah, Al);
        else if (g < 2 * gBc)
            gemm_core<0>(xc, wt_h + 16384, wt_l + 16384, t_cc, Nc, (g - gBc) * 64, threadIdx.x, Ah, Al);
        else
            gemm_core<0>(xg, wt_h + 2 * 16384, wt_l + 2 * 16384, t_gc, Ng, (g - 2 * gBc) * 64, threadIdx.x, Ah, Al);
    } else {
        int eb = q * 5 + (r7 - 2);
        if (eb >= EB) return;
        const int* src; const int* dst; int* sdeg; int* cnt; int* ell; int E; int base;
        if (eb < B0)            { src = s0; dst = d0; sdeg = sd0; cnt = c0; ell = e0; E = E0; base = eb; }
        else if (eb < B0 + B1)  { src = s1; dst = d1; sdeg = sd1; cnt = c1; ell = e1; E = E1; base = eb - B0; }
        else                    { src = s2; dst = d2; sdeg = sd2; cnt = c2; ell = e2; E = E2; base = eb - B0 - B1; }
        int i = base * 256 + threadIdx.x;
        if (i < E) {
            int s = src[i];
            int d = dst[i];
            atomicAdd(&sdeg[s], 1);
            int p = atomicAdd(&cnt[d], 1);
            if (p < ELLW) ell[d * ELLW + p] = s;
        }
    }
}

// ---------------- combined layer-2 GEMM (relu fused) ----------------
__global__ __launch_bounds__(256) void gemm2_both(
    const float* __restrict__ h1c, const float* __restrict__ h1g,
    const __bf16* __restrict__ wt_h, const __bf16* __restrict__ wt_l,
    float* __restrict__ t_cc, float* __restrict__ t_gc, int Nc, int Ng, int gBc)
{
    __shared__ __bf16 Ah[64][136];
    __shared__ __bf16 Al[64][136];
    if ((int)blockIdx.x < gBc)
        gemm_core<1>(h1c, wt_h + 3 * 16384, wt_l + 3 * 16384, t_cc, Nc, blockIdx.x * 64, threadIdx.x, Ah, Al);
    else
        gemm_core<1>(h1g, wt_h + 4 * 16384, wt_l + 4 * 16384, t_gc, Ng, (blockIdx.x - gBc) * 64, threadIdx.x, Ah, Al);
}

// ---------------- gather helper: sum over one relation's ELL row with inline src-norm ----------------
__device__ __forceinline__ void rel_accum(const float* __restrict__ feat,
    const int* __restrict__ cp, int n, const int* __restrict__ sdeg, int c2,
    float& a0, float& a1)
{
    int i = 0;
    for (; i + 3 < n; i += 4) {
        int q0 = cp[i], q1 = cp[i + 1], q2 = cp[i + 2], q3 = cp[i + 3];
        float w0 = rsqrtf(fmaxf((float)sdeg[q0], 1.0f));
        float w1 = rsqrtf(fmaxf((float)sdeg[q1], 1.0f));
        float w2 = rsqrtf(fmaxf((float)sdeg[q2], 1.0f));
        float w3 = rsqrtf(fmaxf((float)sdeg[q3], 1.0f));
        float2 v0 = *(const float2*)(feat + (size_t)q0 * 128 + c2);
        float2 v1 = *(const float2*)(feat + (size_t)q1 * 128 + c2);
        float2 v2 = *(const float2*)(feat + (size_t)q2 * 128 + c2);
        float2 v3 = *(const float2*)(feat + (size_t)q3 * 128 + c2);
        a0 = fmaf(v0.x, w0, a0); a1 = fmaf(v0.y, w0, a1);
        a0 = fmaf(v1.x, w1, a0); a1 = fmaf(v1.y, w1, a1);
        a0 = fmaf(v2.x, w2, a0); a1 = fmaf(v2.y, w2, a1);
        a0 = fmaf(v3.x, w3, a0); a1 = fmaf(v3.y, w3, a1);
    }
    for (; i < n; ++i) {
        int q0 = cp[i];
        float w0 = rsqrtf(fmaxf((float)sdeg[q0], 1.0f));
        float2 v0 = *(const float2*)(feat + (size_t)q0 * 128 + c2);
        a0 = fmaf(v0.x, w0, a0); a1 = fmaf(v0.y, w0, a1);
    }
}

// ---------------- combined layer-1 gathers: blocks < Bg do cg->h1_gene; rest dual cc+gc->h1_chem ----------------
__global__ __launch_bounds__(256) void gather_l1(
    const float* __restrict__ t_cg, const int* __restrict__ ell_cg,
    const int* __restrict__ cnt_cg, const int* __restrict__ degs_cg,
    const float* __restrict__ f_cc, const int* __restrict__ ell_cc,
    const int* __restrict__ cnt_cc, const int* __restrict__ degs_cc,
    const float* __restrict__ t_gc, const int* __restrict__ ell_gc,
    const int* __restrict__ cnt_gc, const int* __restrict__ degs_gc,
    const float* __restrict__ b1_cg, const float* __restrict__ b1_cc, const float* __restrict__ b1_gc,
    float* __restrict__ h1_gene, float* __restrict__ h1_chem, int Ng, int Nc, int Bg)
{
    int lane = threadIdx.x & 63;
    int c2 = lane * 2;
    if ((int)blockIdx.x < Bg) {
        int row = blockIdx.x * 4 + (threadIdx.x >> 6);
        if (row >= Ng) return;
        int n = cnt_cg[row];
        float wd = rsqrtf(fmaxf((float)n, 1.0f));
        if (n > ELLW) n = ELLW;
        float a0 = 0.f, a1 = 0.f;
        rel_accum(t_cg, ell_cg + row * ELLW, n, degs_cg, c2, a0, a1);
        float r0 = fmaf(a0, wd, b1_cg[c2]);
        float r1 = fmaf(a1, wd, b1_cg[c2 + 1]);
        *(float2*)(h1_gene + (size_t)row * 128 + c2) = make_float2(r0, r1);
    } else {
        int row = (blockIdx.x - Bg) * 4 + (threadIdx.x >> 6);
        if (row >= Nc) return;
        int na = cnt_cc[row];
        float wa = rsqrtf(fmaxf((float)na, 1.0f));
        if (na > ELLW) na = ELLW;
        float a0 = 0.f, a1 = 0.f;
        rel_accum(f_cc, ell_cc + row * ELLW, na, degs_cc, c2, a0, a1);
        float r0 = fmaf(a0, wa, b1_cc[c2]);
        float r1 = fmaf(a1, wa, b1_cc[c2 + 1]);
        int nb = cnt_gc[row];
        float wb = rsqrtf(fmaxf((float)nb, 1.0f));
        if (nb > ELLW) nb = ELLW;
        float s0 = 0.f, s1 = 0.f;
        rel_accum(t_gc, ell_gc + row * ELLW, nb, degs_gc, c2, s0, s1);
        r0 += fmaf(s0, wb, b1_gc[c2]);
        r1 += fmaf(s1, wb, b1_gc[c2 + 1]);
        *(float2*)(h1_chem + (size_t)row * 128 + c2) = make_float2(r0, r1);
    }
}

// ---------------- final dual gather -> d_out ----------------
__global__ __launch_bounds__(256) void gather_l2(
    const float* __restrict__ fA, const int* __restrict__ ellA,
    const int* __restrict__ cntA, const int* __restrict__ degsA,
    const float* __restrict__ fB, const int* __restrict__ ellB,
    const int* __restrict__ cntB, const int* __restrict__ degsB,
    const float* __restrict__ bA, const float* __restrict__ bB,
    float* __restrict__ out, int Nd)
{
    int lane = threadIdx.x & 63;
    int c2 = lane * 2;
    int row = blockIdx.x * 4 + (threadIdx.x >> 6);
    if (row >= Nd) return;
    int na = cntA[row];
    float wa = rsqrtf(fmaxf((float)na, 1.0f));
    if (na > ELLW) na = ELLW;
    float a0 = 0.f, a1 = 0.f;
    rel_accum(fA, ellA + row * ELLW, na, degsA, c2, a0, a1);
    float r0 = fmaf(a0, wa, bA[c2]);
    float r1 = fmaf(a1, wa, bA[c2 + 1]);
    int nb = cntB[row];
    float wb = rsqrtf(fmaxf((float)nb, 1.0f));
    if (nb > ELLW) nb = ELLW;
    float s0 = 0.f, s1 = 0.f;
    rel_accum(fB, ellB + row * ELLW, nb, degsB, c2, s0, s1);
    r0 += fmaf(s0, wb, bB[c2]);
    r1 += fmaf(s1, wb, bB[c2 + 1]);
    *(float2*)(out + (size_t)row * 128 + c2) = make_float2(r0, r1);
}

extern "C" void kernel_launch(void* const* d_in, const int* in_sizes, int n_in,
                              void* d_out, int out_size, void* d_ws, size_t ws_size,
                              hipStream_t stream)
{
    const float* x_chem = (const float*)d_in[0];
    const float* x_gene = (const float*)d_in[1];
    const int* src_cc = (const int*)d_in[2];
    const int* dst_cc = (const int*)d_in[3];
    const int* src_cg = (const int*)d_in[4];
    const int* dst_cg = (const int*)d_in[5];
    const int* src_gc = (const int*)d_in[6];
    const int* dst_gc = (const int*)d_in[7];
    const float* W1_cc = (const float*)d_in[8];
    const float* W1_cg = (const float*)d_in[9];
    const float* W1_gc = (const float*)d_in[10];
    const float* W2_cc = (const float*)d_in[11];
    const float* W2_gc = (const float*)d_in[13];
    const float* b1_cc = (const float*)d_in[14];
    const float* b1_cg = (const float*)d_in[15];
    const float* b1_gc = (const float*)d_in[16];
    const float* b2_cc = (const float*)d_in[17];
    const float* b2_gc = (const float*)d_in[19];
    (void)n_in; (void)out_size; (void)ws_size;

    const int Nc = in_sizes[0] / 128;
    const int Ng = in_sizes[1] / 128;
    const int Ecc = in_sizes[2];
    const int Ecg = in_sizes[4];
    const int Egc = in_sizes[6];

    // ---------------- workspace layout ----------------
    int* ip = (int*)d_ws;
    int* cnt_cc  = ip; ip += Nc;   // in-deg cc (zeroed region start)
    int* cnt_cg  = ip; ip += Ng;   // in-deg cg
    int* cnt_gc  = ip; ip += Nc;   // in-deg gc
    int* degs_cc = ip; ip += Nc;   // out-deg chem (cc)
    int* degs_cg = ip; ip += Nc;   // out-deg chem (cg)
    int* degs_gc = ip; ip += Ng;   // out-deg gene (gc)
    const int degTotal = 4 * Nc + 2 * Ng;
    int* ell_cc = ip; ip += (size_t)Nc * ELLW;
    int* ell_cg = ip; ip += (size_t)Ng * ELLW;
    int* ell_gc = ip; ip += (size_t)Nc * ELLW;
    size_t intCount = (size_t)(ip - (int*)d_ws);
    intCount = (intCount + 3) & ~(size_t)3;
    float* fp = (float*)d_ws + intCount;
    float* h1_chem = fp; fp += (size_t)Nc * 128;
    float* h1_gene = fp; fp += (size_t)Ng * 128;
    float* tmp_cg  = fp; fp += (size_t)Nc * 128;   // layer1 cg out; reused as layer2 cc out
    float* tmp_gc  = fp; fp += (size_t)Ng * 128;   // layer1 gc out; reused as layer2 gc out
    __bf16* wt_h = (__bf16*)fp;                    // 5 * 16384 bf16
    __bf16* wt_l = wt_h + 5 * 16384;
    float* outF = (float*)d_out;                   // doubles as layer1 cc scratch

    hipMemsetAsync(d_ws, 0, (size_t)degTotal * sizeof(int), stream);

    dim3 blk(256);
    const int B0 = (Ecc + 255) / 256, B1 = (Ecg + 255) / 256, B2 = (Egc + 255) / 256;
    const int EB = B0 + B1 + B2;
    const int gBc = (Nc + 63) / 64, gBg = (Ng + 63) / 64;
    const int G = 2 * gBc + gBg;
    int Q = (G + 1) / 2;
    if ((EB + 4) / 5 > Q) Q = (EB + 4) / 5;
    const int T = 7 * Q;

    // W prep (feeds the fused kernel's GEMM blocks)
    prep_w<<<dim3(64, 5), blk, 0, stream>>>(W1_cg, W1_cc, W1_gc, W2_cc, W2_gc, wt_h, wt_l);

    // fused: graph build + all three layer-1 GEMMs (unscaled)
    fused_build_gemm<<<T, blk, 0, stream>>>(
        src_cc, dst_cc, degs_cc, cnt_cc, ell_cc, Ecc, B0,
        src_cg, dst_cg, degs_cg, cnt_cg, ell_cg, Ecg, B1,
        src_gc, dst_gc, degs_gc, cnt_gc, ell_gc, Egc,
        x_chem, x_gene, wt_h, wt_l, tmp_cg, outF, tmp_gc,
        Nc, Ng, gBc, G, EB);

    // ---- all layer-1 gathers in one launch (norms computed inline from int degrees) ----
    const int Bg = (Ng + 3) / 4, Bc = (Nc + 3) / 4;
    gather_l1<<<Bg + Bc, blk, 0, stream>>>(
        tmp_cg, ell_cg, cnt_cg, degs_cg,
        outF,  ell_cc, cnt_cc, degs_cc,
        tmp_gc, ell_gc, cnt_gc, degs_gc,
        b1_cg, b1_cc, b1_gc, h1_gene, h1_chem, Ng, Nc, Bg);

    // ---- both layer-2 GEMMs in one launch ----
    gemm2_both<<<gBc + gBg, blk, 0, stream>>>(h1_chem, h1_gene, wt_h, wt_l,
        tmp_cg, tmp_gc, Nc, Ng, gBc);

    // ---- final dual gather -> out ----
    gather_l2<<<Bc, blk, 0, stream>>>(
        tmp_cg, ell_cc, cnt_cc, degs_cc,
        tmp_gc, ell_gc, cnt_gc, degs_gc,
        b2_cc, b2_gc, outF, Nc);
}

// Round 9
// 435.113 us; speedup vs baseline: 1.0891x; 1.0194x over previous
//
#include <hip/hip_runtime.h>
#include <math.h>

#define NEG_SLOPE 0.01f
#define ELLW 40   // max in-degree per relation (Poisson(10); P(overflow)~1e-8, clamped)

typedef float f4 __attribute__((ext_vector_type(4)));
typedef __bf16 bf16x8 __attribute__((ext_vector_type(8)));
typedef __bf16 bf16x4 __attribute__((ext_vector_type(4)));

// ---------------- W prep (transpose + bf16 split, 5 weights) + zero degree region ----------------
__global__ __launch_bounds__(256) void prep_w_zero(
    const float* __restrict__ W0, const float* __restrict__ W1,
    const float* __restrict__ W2, const float* __restrict__ W3,
    const float* __restrict__ W4, __bf16* __restrict__ H, __bf16* __restrict__ L,
    int* __restrict__ zp, int zN)
{
    const int b = blockIdx.x;
    if (b < 320) {
        const int y = b >> 6;
        const float* W = y == 0 ? W0 : y == 1 ? W1 : y == 2 ? W2 : y == 3 ? W3 : W4;
        int idx = (b & 63) * 256 + threadIdx.x;   // 0..16383
        int k = idx >> 7, n = idx & 127;
        float w = W[idx];
        __bf16 h = (__bf16)w;
        __bf16 l = (__bf16)(w - (float)h);
        H[(size_t)y * 16384 + n * 128 + k] = h;
        L[(size_t)y * 16384 + n * 128 + k] = l;
    } else {
        int i = (b - 320) * 256 + threadIdx.x;
        if (i < zN) zp[i] = 0;
    }
}

// ---------------- MFMA GEMM core (bf16 3-split, unscaled): C[64 rows,128] = f(A) @ W ----------------
template <int RELU>
__device__ __forceinline__ void gemm_core(const float* __restrict__ A,
    const __bf16* __restrict__ Bh, const __bf16* __restrict__ Bl,
    float* __restrict__ C, int M, int row0, int tid,
    __bf16 (*Ah)[136], __bf16 (*Al)[136])
{
#pragma unroll
    for (int it = 0; it < 8; ++it) {
        int idx4 = it * 256 + tid;
        int r = idx4 >> 5;
        int c = (idx4 & 31) << 2;
        int rg = row0 + r;
        f4 v = {0.f, 0.f, 0.f, 0.f};
        if (rg < M) v = *(const f4*)(A + (size_t)rg * 128 + c);
        if (RELU) {
#pragma unroll
            for (int j = 0; j < 4; ++j) v[j] = v[j] >= 0.f ? v[j] : v[j] * NEG_SLOPE;
        }
        bf16x4 hv, lv;
#pragma unroll
        for (int j = 0; j < 4; ++j) {
            __bf16 h = (__bf16)v[j];
            hv[j] = h;
            lv[j] = (__bf16)(v[j] - (float)h);
        }
        *(bf16x4*)&Ah[r][c] = hv;
        *(bf16x4*)&Al[r][c] = lv;
    }
    __syncthreads();

    const int lane = tid & 63;
    const int wid = tid >> 6;
    const int lm = lane & 15;
    const int lq = lane >> 4;
    const int mbase = (wid & 1) * 32;
    const int nbase = (wid >> 1) * 64;

    f4 acc[2][4] = {};
#pragma unroll
    for (int kc = 0; kc < 4; ++kc) {
        const int koff = kc * 32 + lq * 8;
        bf16x8 ah[2], al[2], bh[4], bl[4];
#pragma unroll
        for (int mi = 0; mi < 2; ++mi) {
            ah[mi] = *(const bf16x8*)&Ah[mbase + mi * 16 + lm][koff];
            al[mi] = *(const bf16x8*)&Al[mbase + mi * 16 + lm][koff];
        }
#pragma unroll
        for (int ni = 0; ni < 4; ++ni) {
            size_t boff = (size_t)(nbase + ni * 16 + lm) * 128 + koff;
            bh[ni] = *(const bf16x8*)(Bh + boff);
            bl[ni] = *(const bf16x8*)(Bl + boff);
        }
#pragma unroll
        for (int mi = 0; mi < 2; ++mi)
#pragma unroll
            for (int ni = 0; ni < 4; ++ni) {
                acc[mi][ni] = __builtin_amdgcn_mfma_f32_16x16x32_bf16(ah[mi], bh[ni], acc[mi][ni], 0, 0, 0);
                acc[mi][ni] = __builtin_amdgcn_mfma_f32_16x16x32_bf16(al[mi], bh[ni], acc[mi][ni], 0, 0, 0);
                acc[mi][ni] = __builtin_amdgcn_mfma_f32_16x16x32_bf16(ah[mi], bl[ni], acc[mi][ni], 0, 0, 0);
            }
    }

#pragma unroll
    for (int mi = 0; mi < 2; ++mi) {
        int rbase = row0 + mbase + mi * 16 + lq * 4;
#pragma unroll
        for (int r = 0; r < 4; ++r) {
            int row = rbase + r;
            if (row < M) {
#pragma unroll
                for (int ni = 0; ni < 4; ++ni)
                    C[(size_t)row * 128 + nbase + ni * 16 + lm] = acc[mi][ni][r];
            }
        }
    }
}

// ---------------- fused: graph build (atomics, at scattered-RMW ceiling) + layer-1 GEMMs ----------------
// blockIdx.x % 7 in {0,1} -> GEMM tile (BM=64); else -> 256 edges of build (1/thread).
__global__ __launch_bounds__(256) void fused_build_gemm(
    const int* __restrict__ s0, const int* __restrict__ d0, int* sd0, int* c0, int* e0, int E0, int B0,
    const int* __restrict__ s1, const int* __restrict__ d1, int* sd1, int* c1, int* e1, int E1, int B1,
    const int* __restrict__ s2, const int* __restrict__ d2, int* sd2, int* c2, int* e2, int E2,
    const float* __restrict__ xc, const float* __restrict__ xg,
    const __bf16* __restrict__ wt_h, const __bf16* __restrict__ wt_l,
    float* __restrict__ t_cg, float* __restrict__ t_cc, float* __restrict__ t_gc,
    int Nc, int Ng, int gBc, int G, int EB)
{
    __shared__ __bf16 Ah[64][136];
    __shared__ __bf16 Al[64][136];
    const int idx = blockIdx.x;
    const int r7 = idx % 7, q = idx / 7;
    if (r7 < 2) {
        int g = q * 2 + r7;
        if (g >= G) return;
        if (g < gBc)
            gemm_core<0>(xc, wt_h, wt_l, t_cg, Nc, g * 64, threadIdx.x, Ah, Al);
        else if (g < 2 * gBc)
            gemm_core<0>(xc, wt_h + 16384, wt_l + 16384, t_cc, Nc, (g - gBc) * 64, threadIdx.x, Ah, Al);
        else
            gemm_core<0>(xg, wt_h + 2 * 16384, wt_l + 2 * 16384, t_gc, Ng, (g - 2 * gBc) * 64, threadIdx.x, Ah, Al);
    } else {
        int eb = q * 5 + (r7 - 2);
        if (eb >= EB) return;
        const int* src; const int* dst; int* sdeg; int* cnt; int* ell; int E; int base;
        if (eb < B0)            { src = s0; dst = d0; sdeg = sd0; cnt = c0; ell = e0; E = E0; base = eb; }
        else if (eb < B0 + B1)  { src = s1; dst = d1; sdeg = sd1; cnt = c1; ell = e1; E = E1; base = eb - B0; }
        else                    { src = s2; dst = d2; sdeg = sd2; cnt = c2; ell = e2; E = E2; base = eb - B0 - B1; }
        int i = base * 256 + threadIdx.x;
        if (i < E) {
            int s = src[i];
            int d = dst[i];
            atomicAdd(&sdeg[s], 1);
            int p = atomicAdd(&cnt[d], 1);
            if (p < ELLW) ell[d * ELLW + p] = s;
        }
    }
}

// ---------------- combined layer-2 GEMM (relu fused) ----------------
__global__ __launch_bounds__(256) void gemm2_both(
    const float* __restrict__ h1c, const float* __restrict__ h1g,
    const __bf16* __restrict__ wt_h, const __bf16* __restrict__ wt_l,
    float* __restrict__ t_cc, float* __restrict__ t_gc, int Nc, int Ng, int gBc)
{
    __shared__ __bf16 Ah[64][136];
    __shared__ __bf16 Al[64][136];
    if ((int)blockIdx.x < gBc)
        gemm_core<1>(h1c, wt_h + 3 * 16384, wt_l + 3 * 16384, t_cc, Nc, blockIdx.x * 64, threadIdx.x, Ah, Al);
    else
        gemm_core<1>(h1g, wt_h + 4 * 16384, wt_l + 4 * 16384, t_gc, Ng, (blockIdx.x - gBc) * 64, threadIdx.x, Ah, Al);
}

// ---------------- gather helper: half-wave paired-edge accumulate (f4/lane, 32 lanes = full row) ----------------
// half h processes edges h, h+2, h+4, ... ; inline src-norm from int degree
__device__ __forceinline__ void rel_accum4(const float* __restrict__ feat,
    const int* __restrict__ cp, int n, const int* __restrict__ sdeg,
    int half, int c4, f4& acc)
{
    int i = half;
    for (; i + 2 < n; i += 4) {
        int q0 = cp[i], q1 = cp[i + 2];
        float w0 = rsqrtf(fmaxf((float)sdeg[q0], 1.0f));
        float w1 = rsqrtf(fmaxf((float)sdeg[q1], 1.0f));
        f4 v0 = *(const f4*)(feat + (size_t)q0 * 128 + c4);
        f4 v1 = *(const f4*)(feat + (size_t)q1 * 128 + c4);
        acc += v0 * w0;
        acc += v1 * w1;
    }
    if (i < n) {
        int q0 = cp[i];
        float w0 = rsqrtf(fmaxf((float)sdeg[q0], 1.0f));
        f4 v0 = *(const f4*)(feat + (size_t)q0 * 128 + c4);
        acc += v0 * w0;
    }
}

__device__ __forceinline__ f4 xhalf_sum(f4 r)
{
    f4 o;
    o[0] = __shfl_xor(r[0], 32);
    o[1] = __shfl_xor(r[1], 32);
    o[2] = __shfl_xor(r[2], 32);
    o[3] = __shfl_xor(r[3], 32);
    return r + o;
}

// ---------------- combined layer-1 gathers: blocks < Bg do cg->h1_gene; rest dual cc+gc->h1_chem ----------------
__global__ __launch_bounds__(256) void gather_l1(
    const float* __restrict__ t_cg, const int* __restrict__ ell_cg,
    const int* __restrict__ cnt_cg, const int* __restrict__ degs_cg,
    const float* __restrict__ f_cc, const int* __restrict__ ell_cc,
    const int* __restrict__ cnt_cc, const int* __restrict__ degs_cc,
    const float* __restrict__ t_gc, const int* __restrict__ ell_gc,
    const int* __restrict__ cnt_gc, const int* __restrict__ degs_gc,
    const float* __restrict__ b1_cg, const float* __restrict__ b1_cc, const float* __restrict__ b1_gc,
    float* __restrict__ h1_gene, float* __restrict__ h1_chem, int Ng, int Nc, int Bg)
{
    const int lane = threadIdx.x & 63;
    const int half = lane >> 5;
    const int c4 = (lane & 31) << 2;
    if ((int)blockIdx.x < Bg) {
        int row = blockIdx.x * 4 + (threadIdx.x >> 6);
        if (row >= Ng) return;
        int n = cnt_cg[row];
        float wd = rsqrtf(fmaxf((float)n, 1.0f));
        if (n > ELLW) n = ELLW;
        f4 acc = {0.f, 0.f, 0.f, 0.f};
        rel_accum4(t_cg, ell_cg + row * ELLW, n, degs_cg, half, c4, acc);
        f4 r = acc * wd;
        r = xhalf_sum(r);
        if (half == 0) {
            r += *(const f4*)(b1_cg + c4);
            *(f4*)(h1_gene + (size_t)row * 128 + c4) = r;
        }
    } else {
        int row = (blockIdx.x - Bg) * 4 + (threadIdx.x >> 6);
        if (row >= Nc) return;
        int na = cnt_cc[row];
        float wa = rsqrtf(fmaxf((float)na, 1.0f));
        if (na > ELLW) na = ELLW;
        f4 accA = {0.f, 0.f, 0.f, 0.f};
        rel_accum4(f_cc, ell_cc + row * ELLW, na, degs_cc, half, c4, accA);
        int nb = cnt_gc[row];
        float wb = rsqrtf(fmaxf((float)nb, 1.0f));
        if (nb > ELLW) nb = ELLW;
        f4 accB = {0.f, 0.f, 0.f, 0.f};
        rel_accum4(t_gc, ell_gc + row * ELLW, nb, degs_gc, half, c4, accB);
        f4 r = accA * wa + accB * wb;
        r = xhalf_sum(r);
        if (half == 0) {
            r += *(const f4*)(b1_cc + c4);
            r += *(const f4*)(b1_gc + c4);
            *(f4*)(h1_chem + (size_t)row * 128 + c4) = r;
        }
    }
}

// ---------------- final dual gather -> d_out ----------------
__global__ __launch_bounds__(256) void gather_l2(
    const float* __restrict__ fA, const int* __restrict__ ellA,
    const int* __restrict__ cntA, const int* __restrict__ degsA,
    const float* __restrict__ fB, const int* __restrict__ ellB,
    const int* __restrict__ cntB, const int* __restrict__ degsB,
    const float* __restrict__ bA, const float* __restrict__ bB,
    float* __restrict__ out, int Nd)
{
    const int lane = threadIdx.x & 63;
    const int half = lane >> 5;
    const int c4 = (lane & 31) << 2;
    int row = blockIdx.x * 4 + (threadIdx.x >> 6);
    if (row >= Nd) return;
    int na = cntA[row];
    float wa = rsqrtf(fmaxf((float)na, 1.0f));
    if (na > ELLW) na = ELLW;
    f4 accA = {0.f, 0.f, 0.f, 0.f};
    rel_accum4(fA, ellA + row * ELLW, na, degsA, half, c4, accA);
    int nb = cntB[row];
    float wb = rsqrtf(fmaxf((float)nb, 1.0f));
    if (nb > ELLW) nb = ELLW;
    f4 accB = {0.f, 0.f, 0.f, 0.f};
    rel_accum4(fB, ellB + row * ELLW, nb, degsB, half, c4, accB);
    f4 r = accA * wa + accB * wb;
    r = xhalf_sum(r);
    if (half == 0) {
        r += *(const f4*)(bA + c4);
        r += *(const f4*)(bB + c4);
        *(f4*)(out + (size_t)row * 128 + c4) = r;
    }
}

extern "C" void kernel_launch(void* const* d_in, const int* in_sizes, int n_in,
                              void* d_out, int out_size, void* d_ws, size_t ws_size,
                              hipStream_t stream)
{
    const float* x_chem = (const float*)d_in[0];
    const float* x_gene = (const float*)d_in[1];
    const int* src_cc = (const int*)d_in[2];
    const int* dst_cc = (const int*)d_in[3];
    const int* src_cg = (const int*)d_in[4];
    const int* dst_cg = (const int*)d_in[5];
    const int* src_gc = (const int*)d_in[6];
    const int* dst_gc = (const int*)d_in[7];
    const float* W1_cc = (const float*)d_in[8];
    const float* W1_cg = (const float*)d_in[9];
    const float* W1_gc = (const float*)d_in[10];
    const float* W2_cc = (const float*)d_in[11];
    const float* W2_gc = (const float*)d_in[13];
    const float* b1_cc = (const float*)d_in[14];
    const float* b1_cg = (const float*)d_in[15];
    const float* b1_gc = (const float*)d_in[16];
    const float* b2_cc = (const float*)d_in[17];
    const float* b2_gc = (const float*)d_in[19];
    (void)n_in; (void)out_size; (void)ws_size;

    const int Nc = in_sizes[0] / 128;
    const int Ng = in_sizes[1] / 128;
    const int Ecc = in_sizes[2];
    const int Ecg = in_sizes[4];
    const int Egc = in_sizes[6];

    // ---------------- workspace layout ----------------
    int* ip = (int*)d_ws;
    int* cnt_cc  = ip; ip += Nc;   // in-deg cc (zeroed region start)
    int* cnt_cg  = ip; ip += Ng;   // in-deg cg
    int* cnt_gc  = ip; ip += Nc;   // in-deg gc
    int* degs_cc = ip; ip += Nc;   // out-deg chem (cc)
    int* degs_cg = ip; ip += Nc;   // out-deg chem (cg)
    int* degs_gc = ip; ip += Ng;   // out-deg gene (gc)
    const int degTotal = 4 * Nc + 2 * Ng;
    int* ell_cc = ip; ip += (size_t)Nc * ELLW;
    int* ell_cg = ip; ip += (size_t)Ng * ELLW;
    int* ell_gc = ip; ip += (size_t)Nc * ELLW;
    size_t intCount = (size_t)(ip - (int*)d_ws);
    intCount = (intCount + 3) & ~(size_t)3;
    float* fp = (float*)d_ws + intCount;
    float* h1_chem = fp; fp += (size_t)Nc * 128;
    float* h1_gene = fp; fp += (size_t)Ng * 128;
    float* tmp_cg  = fp; fp += (size_t)Nc * 128;   // layer1 cg out; reused as layer2 cc out
    float* tmp_gc  = fp; fp += (size_t)Ng * 128;   // layer1 gc out; reused as layer2 gc out
    __bf16* wt_h = (__bf16*)fp;                    // 5 * 16384 bf16
    __bf16* wt_l = wt_h + 5 * 16384;
    float* outF = (float*)d_out;                   // doubles as layer1 cc scratch

    dim3 blk(256);
    const int B0 = (Ecc + 255) / 256, B1 = (Ecg + 255) / 256, B2 = (Egc + 255) / 256;
    const int EB = B0 + B1 + B2;
    const int gBc = (Nc + 63) / 64, gBg = (Ng + 63) / 64;
    const int G = 2 * gBc + gBg;
    int Q = (G + 1) / 2;
    if ((EB + 4) / 5 > Q) Q = (EB + 4) / 5;
    const int T = 7 * Q;

    // W prep + zero degree region (one kernel)
    const int zB = (degTotal + 255) / 256;
    prep_w_zero<<<320 + zB, blk, 0, stream>>>(W1_cg, W1_cc, W1_gc, W2_cc, W2_gc,
        wt_h, wt_l, (int*)d_ws, degTotal);

    // fused: graph build + all three layer-1 GEMMs (unscaled)
    fused_build_gemm<<<T, blk, 0, stream>>>(
        src_cc, dst_cc, degs_cc, cnt_cc, ell_cc, Ecc, B0,
        src_cg, dst_cg, degs_cg, cnt_cg, ell_cg, Ecg, B1,
        src_gc, dst_gc, degs_gc, cnt_gc, ell_gc, Egc,
        x_chem, x_gene, wt_h, wt_l, tmp_cg, outF, tmp_gc,
        Nc, Ng, gBc, G, EB);

    // ---- all layer-1 gathers in one launch (norms computed inline from int degrees) ----
    const int Bg = (Ng + 3) / 4, Bc = (Nc + 3) / 4;
    gather_l1<<<Bg + Bc, blk, 0, stream>>>(
        tmp_cg, ell_cg, cnt_cg, degs_cg,
        outF,  ell_cc, cnt_cc, degs_cc,
        tmp_gc, ell_gc, cnt_gc, degs_gc,
        b1_cg, b1_cc, b1_gc, h1_gene, h1_chem, Ng, Nc, Bg);

    // ---- both layer-2 GEMMs in one launch ----
    gemm2_both<<<gBc + gBg, blk, 0, stream>>>(h1_chem, h1_gene, wt_h, wt_l,
        tmp_cg, tmp_gc, Nc, Ng, gBc);

    // ---- final dual gather -> out ----
    gather_l2<<<Bc, blk, 0, stream>>>(
        tmp_cg, ell_cc, cnt_cc, degs_cc,
        tmp_gc, ell_gc, cnt_gc, degs_gc,
        b2_cc, b2_gc, outF, Nc);
}